// Round 1
// baseline (1577.793 us; speedup 1.0000x reference)
//
#include <hip/hip_runtime.h>
#include <hip/hip_fp16.h>
#include <stdint.h>

typedef _Float16 f16x8 __attribute__((ext_vector_type(8)));
typedef _Float16 f16x4 __attribute__((ext_vector_type(4)));
typedef float    f32x4 __attribute__((ext_vector_type(4)));

static constexpr int NROWS = 32768;   // b*n = 8*4096
static constexpr int NCODE = 8192;    // codebook size
static constexpr int DDIM  = 512;
static constexpr int BM = 128, BN = 128, BK = 64;
static constexpr int NCB   = NCODE / BN;   // 64 column blocks
static constexpr int NPART = NCB * 2;      // 128 partial argmins per row (2 wave-cols/block)

// out layout (floats): quantize [NROWS*DDIM] | embed_ind [NROWS] | dist [NROWS*NCODE]
static constexpr size_t OFF_IND  = (size_t)NROWS * DDIM;          // 16777216
static constexpr size_t OFF_DIST = OFF_IND + NROWS;               // 16809984

// ws layout (bytes)
static constexpr size_t WS_XH   = 0;
static constexpr size_t WS_XL   = WS_XH + (size_t)NROWS * DDIM * 2;   // 33554432
static constexpr size_t WS_EH   = WS_XL + (size_t)NROWS * DDIM * 2;   // 67108864
static constexpr size_t WS_EL   = WS_EH + (size_t)NCODE * DDIM * 2;   // 75497472
static constexpr size_t WS_X2   = WS_EL + (size_t)NCODE * DDIM * 2;   // 83886080
static constexpr size_t WS_E2   = WS_X2 + (size_t)NROWS * 4;          // 84017152
static constexpr size_t WS_PART = WS_E2 + (size_t)NCODE * 4;          // 84049920
// end = WS_PART + NROWS*NPART*8 = 117604352 bytes

__device__ inline void gload_lds16(const void* g, void* l) {
  __builtin_amdgcn_global_load_lds((const __attribute__((address_space(1))) void*)g,
                                   (__attribute__((address_space(3))) void*)l,
                                   16, 0, 0);
}

// ---------- prep: fp32 -> (f16 hi, f16 lo) split + fp64-accumulated norms ----------
__global__ __launch_bounds__(128)
void prep_kernel(const float* __restrict__ x, const float* __restrict__ e,
                 _Float16* __restrict__ xh, _Float16* __restrict__ xl,
                 _Float16* __restrict__ eh, _Float16* __restrict__ el,
                 float* __restrict__ x2, float* __restrict__ e2)
{
  int bid = blockIdx.x;
  const float* src; _Float16 *dh, *dl; float* nrm;
  if (bid < NROWS) {
    src = x + (size_t)bid * DDIM;
    dh = xh + (size_t)bid * DDIM;  dl = xl + (size_t)bid * DDIM;
    nrm = x2 + bid;
  } else {
    int r = bid - NROWS;
    src = e + (size_t)r * DDIM;
    dh = eh + (size_t)r * DDIM;    dl = el + (size_t)r * DDIM;
    nrm = e2 + r;
  }
  int t = threadIdx.x;                       // 128 threads * 4 floats = 512
  float4 v = reinterpret_cast<const float4*>(src)[t];
  double s = (double)v.x*v.x + (double)v.y*v.y + (double)v.z*v.z + (double)v.w*v.w;
  f16x4 h, l;
  h.x = (_Float16)v.x; l.x = (_Float16)(v.x - (float)h.x);
  h.y = (_Float16)v.y; l.y = (_Float16)(v.y - (float)h.y);
  h.z = (_Float16)v.z; l.z = (_Float16)(v.z - (float)h.z);
  h.w = (_Float16)v.w; l.w = (_Float16)(v.w - (float)h.w);
  reinterpret_cast<f16x4*>(dh)[t] = h;
  reinterpret_cast<f16x4*>(dl)[t] = l;
  #pragma unroll
  for (int m = 1; m < 64; m <<= 1) s += __shfl_xor(s, m);
  __shared__ double sh[2];
  if ((t & 63) == 0) sh[t >> 6] = s;
  __syncthreads();
  if (t == 0) nrm[0] = (float)(sh[0] + sh[1]);
}

// ---------- main: fused split-GEMM (K_eff = 3*512) + dist epilogue + partial argmin ----------
// acc = xh*eh^T + xh*el^T + xl*eh^T  over k-tiles; d2 = x2 + e2 - 2*acc; dist = -sqrt(max(d2,0))
__global__ __launch_bounds__(256)
void dist_gemm_kernel(const _Float16* __restrict__ xh, const _Float16* __restrict__ xl,
                      const _Float16* __restrict__ eh, const _Float16* __restrict__ el,
                      const float* __restrict__ x2, const float* __restrict__ e2,
                      float* __restrict__ dist, float2* __restrict__ part)
{
  __shared__ __align__(16) _Float16 At[BM][BK];   // 16 KB
  __shared__ __align__(16) _Float16 Bt[BN][BK];   // 16 KB

  const int bn = blockIdx.x;            // 0..63  (code/col block)
  const int bm = blockIdx.y;            // 0..255 (row block)
  const int tid  = threadIdx.x;
  const int wid  = tid >> 6;
  const int lane = tid & 63;
  const int wr = wid >> 1, wc = wid & 1;        // 2x2 waves, each 64x64 out

  const int row_blk = bm * BM;
  const int col_blk = bn * BN;

  // staging lane mapping: per gload instruction the wave fills 1024B = 8 rows x 128B
  const int sr = lane >> 3;             // row within 8-row chunk
  const int sc = (lane & 7) * 8;        // f16 col offset

  f32x4 acc[4][4] = {};

  for (int t = 0; t < 24; ++t) {
    const int seg = t >> 3;                       // 0: hh  1: h*el  2: xl*eh
    const int k0  = (t & 7) * BK;
    const _Float16* As = (seg < 2)  ? xh : xl;
    const _Float16* Bs = (seg == 1) ? el : eh;

    __syncthreads();   // previous tile's reads complete before overwrite
    #pragma unroll
    for (int i = 0; i < 4; ++i) {
      int chunk = wid * 4 + i;                    // 16 chunks of 8 rows
      const _Float16* ga = As + (size_t)(row_blk + chunk * 8 + sr) * DDIM + k0 + sc;
      gload_lds16(ga, &At[chunk * 8][0]);
    }
    #pragma unroll
    for (int i = 0; i < 4; ++i) {
      int chunk = wid * 4 + i;
      const _Float16* gb = Bs + (size_t)(col_blk + chunk * 8 + sr) * DDIM + k0 + sc;
      gload_lds16(gb, &Bt[chunk * 8][0]);
    }
    __syncthreads();   // compiler drains vmcnt before barrier

    #pragma unroll
    for (int ks = 0; ks < 2; ++ks) {
      const int kb = ks * 32 + ((lane >> 4) * 8);   // f16 k-offset for this lane
      f16x8 af[4], bf[4];
      #pragma unroll
      for (int m = 0; m < 4; ++m)
        af[m] = *(const f16x8*)&At[wr * 64 + m * 16 + (lane & 15)][kb];
      #pragma unroll
      for (int n = 0; n < 4; ++n)
        bf[n] = *(const f16x8*)&Bt[wc * 64 + n * 16 + (lane & 15)][kb];
      #pragma unroll
      for (int m = 0; m < 4; ++m)
        #pragma unroll
        for (int n = 0; n < 4; ++n)
          acc[m][n] = __builtin_amdgcn_mfma_f32_16x16x32_f16(af[m], bf[n], acc[m][n], 0, 0, 0);
    }
  }

  // ---- epilogue: dist + per-wave per-row argmin ----
  const int row0 = row_blk + wr * 64;
  const int col0 = col_blk + wc * 64;
  const int q    = lane >> 4;           // quarter (row sub-offset q*4)
  const int csub = lane & 15;

  float e2v[4];
  #pragma unroll
  for (int n = 0; n < 4; ++n) e2v[n] = e2[col0 + n * 16 + csub];

  float bestv[16], besti[16];
  #pragma unroll
  for (int m = 0; m < 4; ++m) {
    #pragma unroll
    for (int j = 0; j < 4; ++j) {
      const int row = row0 + m * 16 + q * 4 + j;
      const float xv = x2[row];
      float* drow = dist + (size_t)row * NCODE;
      float bv = -3.0e38f, bi = 0.0f;
      #pragma unroll
      for (int n = 0; n < 4; ++n) {
        const int col = col0 + n * 16 + csub;
        float xe = acc[m][n][j];
        float d2 = (xv + e2v[n]) - 2.0f * xe;
        d2 = fmaxf(d2, 0.0f);
        float dv = -sqrtf(d2);
        drow[col] = dv;
        if (dv > bv) { bv = dv; bi = (float)col; }   // ascending col => first-max kept
      }
      bestv[m * 4 + j] = bv;
      besti[m * 4 + j] = bi;
    }
  }

  // reduce across the 16 lanes sharing each row (argmax of dist, tie -> min index)
  #pragma unroll
  for (int msk = 1; msk < 16; msk <<= 1) {
    #pragma unroll
    for (int r = 0; r < 16; ++r) {
      float ov = __shfl_xor(bestv[r], msk);
      float oi = __shfl_xor(besti[r], msk);
      if (ov > bestv[r] || (ov == bestv[r] && oi < besti[r])) { bestv[r] = ov; besti[r] = oi; }
    }
  }
  if (csub == 0) {
    #pragma unroll
    for (int m = 0; m < 4; ++m)
      #pragma unroll
      for (int j = 0; j < 4; ++j) {
        const int row = row0 + m * 16 + q * 4 + j;
        part[(size_t)row * NPART + bn * 2 + wc] = make_float2(bestv[m * 4 + j], besti[m * 4 + j]);
      }
  }
}

// ---------- final: per-row reduce of 128 partials, write index (as float), gather code row ----------
__global__ __launch_bounds__(64)
void reduce_gather_kernel(const float2* __restrict__ part, const float* __restrict__ embed,
                          float* __restrict__ quant, float* __restrict__ ind)
{
  const int row = blockIdx.x;
  const int l = threadIdx.x;
  float2 a = part[(size_t)row * NPART + l];
  float2 b = part[(size_t)row * NPART + 64 + l];
  float bv = a.x, bi = a.y;
  if (b.x > bv || (b.x == bv && b.y < bi)) { bv = b.x; bi = b.y; }
  #pragma unroll
  for (int m = 1; m < 64; m <<= 1) {
    float ov = __shfl_xor(bv, m);
    float oi = __shfl_xor(bi, m);
    if (ov > bv || (ov == bv && oi < bi)) { bv = ov; bi = oi; }
  }
  if (l == 0) ind[row] = bi;
  const int idx = (int)bi;
  const float4* src = reinterpret_cast<const float4*>(embed + (size_t)idx * DDIM);
  float4* dst = reinterpret_cast<float4*>(quant + (size_t)row * DDIM);
  dst[l]      = src[l];
  dst[l + 64] = src[l + 64];
}

extern "C" void kernel_launch(void* const* d_in, const int* in_sizes, int n_in,
                              void* d_out, int out_size, void* d_ws, size_t ws_size,
                              hipStream_t stream) {
  const float* x     = (const float*)d_in[0];
  const float* embed = (const float*)d_in[1];

  char* ws = (char*)d_ws;
  _Float16* xh = (_Float16*)(ws + WS_XH);
  _Float16* xl = (_Float16*)(ws + WS_XL);
  _Float16* eh = (_Float16*)(ws + WS_EH);
  _Float16* el = (_Float16*)(ws + WS_EL);
  float*    x2 = (float*)(ws + WS_X2);
  float*    e2 = (float*)(ws + WS_E2);
  float2*   part = (float2*)(ws + WS_PART);

  float* quant = (float*)d_out;
  float* ind   = (float*)d_out + OFF_IND;
  float* dist  = (float*)d_out + OFF_DIST;

  prep_kernel<<<dim3(NROWS + NCODE), 128, 0, stream>>>(x, embed, xh, xl, eh, el, x2, e2);
  dist_gemm_kernel<<<dim3(NCB, NROWS / BM), 256, 0, stream>>>(xh, xl, eh, el, x2, e2, dist, part);
  reduce_gather_kernel<<<dim3(NROWS), 64, 0, stream>>>(part, embed, quant, ind);
}

// Round 2
// 1115.268 us; speedup vs baseline: 1.4147x; 1.4147x over previous
//
#include <hip/hip_runtime.h>
#include <hip/hip_fp16.h>
#include <stdint.h>

typedef _Float16 f16x8 __attribute__((ext_vector_type(8)));
typedef _Float16 f16x4 __attribute__((ext_vector_type(4)));
typedef float    f32x4 __attribute__((ext_vector_type(4)));

static constexpr int NROWS = 32768;   // b*n
static constexpr int NCODE = 8192;
static constexpr int DDIM  = 512;
static constexpr int BM = 256, BN = 256, BK = 64;
static constexpr int NBM = NROWS / BM;    // 128
static constexpr int NBN = NCODE / BN;    // 32
static constexpr int NPART = NBN * 2;     // 64 partials per row

// out layout (floats): quantize [NROWS*DDIM] | embed_ind [NROWS] | dist [NROWS*NCODE]
static constexpr size_t OFF_IND  = (size_t)NROWS * DDIM;
static constexpr size_t OFF_DIST = OFF_IND + NROWS;

// ws layout (bytes)
static constexpr size_t WS_XH   = 0;
static constexpr size_t WS_XL   = WS_XH + (size_t)NROWS * DDIM * 2;
static constexpr size_t WS_EH   = WS_XL + (size_t)NROWS * DDIM * 2;
static constexpr size_t WS_EL   = WS_EH + (size_t)NCODE * DDIM * 2;
static constexpr size_t WS_X2   = WS_EL + (size_t)NCODE * DDIM * 2;
static constexpr size_t WS_E2   = WS_X2 + (size_t)NROWS * 4;
static constexpr size_t WS_PART = WS_E2 + (size_t)NCODE * 4;

__device__ inline void gload_lds16(const void* g, void* l) {
  __builtin_amdgcn_global_load_lds((const __attribute__((address_space(1))) void*)g,
                                   (__attribute__((address_space(3))) void*)l,
                                   16, 0, 0);
}

// ---------- prep: fp32 -> (f16 hi, f16 lo) split + fp64-accumulated norms ----------
__global__ __launch_bounds__(128)
void prep_kernel(const float* __restrict__ x, const float* __restrict__ e,
                 _Float16* __restrict__ xh, _Float16* __restrict__ xl,
                 _Float16* __restrict__ eh, _Float16* __restrict__ el,
                 float* __restrict__ x2, float* __restrict__ e2)
{
  int bid = blockIdx.x;
  const float* src; _Float16 *dh, *dl; float* nrm;
  if (bid < NROWS) {
    src = x + (size_t)bid * DDIM;
    dh = xh + (size_t)bid * DDIM;  dl = xl + (size_t)bid * DDIM;
    nrm = x2 + bid;
  } else {
    int r = bid - NROWS;
    src = e + (size_t)r * DDIM;
    dh = eh + (size_t)r * DDIM;    dl = el + (size_t)r * DDIM;
    nrm = e2 + r;
  }
  int t = threadIdx.x;
  float4 v = reinterpret_cast<const float4*>(src)[t];
  double s = (double)v.x*v.x + (double)v.y*v.y + (double)v.z*v.z + (double)v.w*v.w;
  f16x4 h, l;
  h.x = (_Float16)v.x; l.x = (_Float16)(v.x - (float)h.x);
  h.y = (_Float16)v.y; l.y = (_Float16)(v.y - (float)h.y);
  h.z = (_Float16)v.z; l.z = (_Float16)(v.z - (float)h.z);
  h.w = (_Float16)v.w; l.w = (_Float16)(v.w - (float)h.w);
  reinterpret_cast<f16x4*>(dh)[t] = h;
  reinterpret_cast<f16x4*>(dl)[t] = l;
  #pragma unroll
  for (int m = 1; m < 64; m <<= 1) s += __shfl_xor(s, m);
  __shared__ double sh[2];
  if ((t & 63) == 0) sh[t >> 6] = s;
  __syncthreads();
  if (t == 0) nrm[0] = (float)(sh[0] + sh[1]);
}

// ---------- main: 256x256 8-phase split-GEMM + dist epilogue + partial argmin ----------
__global__ __launch_bounds__(512, 2)
void dist_gemm_kernel(const _Float16* __restrict__ xh, const _Float16* __restrict__ xl,
                      const _Float16* __restrict__ eh, const _Float16* __restrict__ el,
                      const float* __restrict__ x2, const float* __restrict__ e2,
                      float* __restrict__ dist, float2* __restrict__ part)
{
  __shared__ _Float16 L[2][2][BM * BK];   // [buf][A=0/B=1][256*64] = 128 KiB

  const int tid  = threadIdx.x;
  const int wid  = tid >> 6;
  const int lane = tid & 63;
  const int qwr  = wid >> 1;      // 0..3 : 32-row band within a 128-row quadrant half
  const int qwc  = wid & 1;       // 0..1 : 64-col half within a 128-col quadrant half

  // XCD-bijective block swizzle (gridDim.x = 4096, divisible by 8)
  const int flat = blockIdx.x;
  const int swz  = (flat & 7) * (int)(gridDim.x >> 3) + (flat >> 3);
  const int bm = swz >> 5;
  const int bn = swz & 31;
  const int R  = bm * BM;
  const int Cc = bn * BN;

  // staging geometry: idx = g*512 + tid covers (row = g*64 + wid*8 + (lane>>3), slot = lane&7)
  const int l3 = lane >> 3;
  const int l7 = lane & 7;
  const int srcslot = ((l7 ^ l3) << 4);   // pre-swizzled global 16B-slot (inverse of read swizzle)

  auto STAGE = [&](int t, int nb) {
    const _Float16* As = (t < 16) ? xh : xl;
    const _Float16* Bs = (t < 8 || t >= 16) ? eh : el;
    const int k0b = (t & 7) * (BK * 2);   // byte offset along K
    #pragma unroll
    for (int h = 0; h < 2; ++h) {
      #pragma unroll
      for (int g = 0; g < 2; ++g) {
        const int r = h * 128 + g * 64 + wid * 8 + l3;
        gload_lds16((const char*)As + (size_t)(R + r) * (DDIM * 2) + k0b + srcslot,
                    &L[nb][0][(h * 128 + g * 64 + wid * 8) * BK]);
        gload_lds16((const char*)Bs + (size_t)(Cc + r) * (DDIM * 2) + k0b + srcslot,
                    &L[nb][1][(h * 128 + g * 64 + wid * 8) * BK]);
      }
    }
  };

  const int l15   = lane & 15;
  const int kslot = (lane >> 4) << 4;     // 0,16,32,48 byte k-slot

  auto LDA = [&](f16x8 (&af)[2][2], int b, int mq) {
    #pragma unroll
    for (int m = 0; m < 2; ++m)
      #pragma unroll
      for (int ks = 0; ks < 2; ++ks) {
        const int row = mq * 128 + qwr * 32 + m * 16 + l15;
        const int kb  = (ks * 64 + kslot) ^ ((row & 7) << 4);   // read-side swizzle
        af[m][ks] = *(const f16x8*)((const char*)&L[b][0][0] + row * 128 + kb);
      }
  };
  auto LDB = [&](f16x8 (&bf)[4][2], int b, int nq) {
    #pragma unroll
    for (int n = 0; n < 4; ++n)
      #pragma unroll
      for (int ks = 0; ks < 2; ++ks) {
        const int row = nq * 128 + qwc * 64 + n * 16 + l15;
        const int kb  = (ks * 64 + kslot) ^ ((row & 7) << 4);
        bf[n][ks] = *(const f16x8*)((const char*)&L[b][1][0] + row * 128 + kb);
      }
  };

  f32x4 acc[2][2][2][4] = {};   // [mq][nq][m][n]

  auto MM = [&](f32x4 (&ac)[2][4], f16x8 (&af)[2][2], f16x8 (&bf)[4][2]) {
    #pragma unroll
    for (int m = 0; m < 2; ++m)
      #pragma unroll
      for (int n = 0; n < 4; ++n)
        #pragma unroll
        for (int ks = 0; ks < 2; ++ks)
          ac[m][n] = __builtin_amdgcn_mfma_f32_16x16x32_f16(af[m][ks], bf[n][ks], ac[m][n], 0, 0, 0);
  };

  // prologue: tile 0 -> buf 0
  STAGE(0, 0);
  asm volatile("s_waitcnt vmcnt(0)" ::: "memory");
  __builtin_amdgcn_s_barrier();

  for (int t = 0; t < 24; ++t) {
    const int b = t & 1;
    f16x8 af[2][2], bf0[4][2], bf1[4][2];

    // p1: quadrant (0,0) — prefetch full next tile into other buffer
    if (t + 1 < 24) STAGE(t + 1, b ^ 1);
    LDA(af, b, 0);
    LDB(bf0, b, 0);
    __builtin_amdgcn_s_barrier();
    __builtin_amdgcn_s_setprio(1);
    MM(acc[0][0], af, bf0);
    __builtin_amdgcn_s_setprio(0);
    __builtin_amdgcn_s_barrier();

    // p2: quadrant (0,1)
    LDB(bf1, b, 1);
    __builtin_amdgcn_s_barrier();
    __builtin_amdgcn_s_setprio(1);
    MM(acc[0][1], af, bf1);
    __builtin_amdgcn_s_setprio(0);
    __builtin_amdgcn_s_barrier();

    // p3: quadrant (1,0)
    LDA(af, b, 1);
    __builtin_amdgcn_s_barrier();
    __builtin_amdgcn_s_setprio(1);
    MM(acc[1][0], af, bf0);
    __builtin_amdgcn_s_setprio(0);
    __builtin_amdgcn_s_barrier();

    // p4: quadrant (1,1) — single per-tile vmcnt wait, 3 phases after issue
    __builtin_amdgcn_s_setprio(1);
    MM(acc[1][1], af, bf1);
    __builtin_amdgcn_s_setprio(0);
    asm volatile("s_waitcnt vmcnt(0)" ::: "memory");
    __builtin_amdgcn_s_barrier();
  }

  // ---- epilogue: dist + per-wave per-row argmin ----
  const int q    = lane >> 4;
  const int csub = lane & 15;

  float e2v[2][4];
  #pragma unroll
  for (int nq = 0; nq < 2; ++nq)
    #pragma unroll
    for (int n = 0; n < 4; ++n)
      e2v[nq][n] = e2[Cc + nq * 128 + qwc * 64 + n * 16 + csub];

  float bestv[16], besti[16];
  int rix = 0;
  #pragma unroll
  for (int mq = 0; mq < 2; ++mq)
    #pragma unroll
    for (int m = 0; m < 2; ++m)
      #pragma unroll
      for (int j = 0; j < 4; ++j, ++rix) {
        const int row = R + mq * 128 + qwr * 32 + m * 16 + q * 4 + j;
        const float xv = x2[row];
        float* drow = dist + (size_t)row * NCODE;
        float bv = -3.0e38f, bi = 0.0f;
        #pragma unroll
        for (int nq = 0; nq < 2; ++nq)
          #pragma unroll
          for (int n = 0; n < 4; ++n) {
            const int col = Cc + nq * 128 + qwc * 64 + n * 16 + csub;
            float xe = acc[mq][nq][m][n][j];
            float d2 = fmaxf((xv + e2v[nq][n]) - 2.0f * xe, 0.0f);
            float dv = -sqrtf(d2);
            drow[col] = dv;
            if (dv > bv) { bv = dv; bi = (float)col; }   // cols ascending => first-max kept
          }
        bestv[rix] = bv;
        besti[rix] = bi;
      }

  // reduce across the 16 lanes sharing each row
  #pragma unroll
  for (int msk = 1; msk < 16; msk <<= 1) {
    #pragma unroll
    for (int r = 0; r < 16; ++r) {
      float ov = __shfl_xor(bestv[r], msk);
      float oi = __shfl_xor(besti[r], msk);
      if (ov > bestv[r] || (ov == bestv[r] && oi < besti[r])) { bestv[r] = ov; besti[r] = oi; }
    }
  }
  if (csub == 0) {
    int rr = 0;
    #pragma unroll
    for (int mq = 0; mq < 2; ++mq)
      #pragma unroll
      for (int m = 0; m < 2; ++m)
        #pragma unroll
        for (int j = 0; j < 4; ++j, ++rr) {
          const int row = R + mq * 128 + qwr * 32 + m * 16 + q * 4 + j;
          part[(size_t)row * NPART + bn * 2 + qwc] = make_float2(bestv[rr], besti[rr]);
        }
  }
}

// ---------- final: per-row reduce of 64 partials, write index, gather code row ----------
__global__ __launch_bounds__(64)
void reduce_gather_kernel(const float2* __restrict__ part, const float* __restrict__ embed,
                          float* __restrict__ quant, float* __restrict__ ind)
{
  const int row = blockIdx.x;
  const int l = threadIdx.x;
  float2 a = part[(size_t)row * NPART + l];
  float bv = a.x, bi = a.y;
  #pragma unroll
  for (int m = 1; m < 64; m <<= 1) {
    float ov = __shfl_xor(bv, m);
    float oi = __shfl_xor(bi, m);
    if (ov > bv || (ov == bv && oi < bi)) { bv = ov; bi = oi; }
  }
  if (l == 0) ind[row] = bi;
  const int idx = (int)bi;
  const float4* src = reinterpret_cast<const float4*>(embed + (size_t)idx * DDIM);
  float4* dst = reinterpret_cast<float4*>(quant + (size_t)row * DDIM);
  dst[l]      = src[l];
  dst[l + 64] = src[l + 64];
}

extern "C" void kernel_launch(void* const* d_in, const int* in_sizes, int n_in,
                              void* d_out, int out_size, void* d_ws, size_t ws_size,
                              hipStream_t stream) {
  const float* x     = (const float*)d_in[0];
  const float* embed = (const float*)d_in[1];

  char* ws = (char*)d_ws;
  _Float16* xh = (_Float16*)(ws + WS_XH);
  _Float16* xl = (_Float16*)(ws + WS_XL);
  _Float16* eh = (_Float16*)(ws + WS_EH);
  _Float16* el = (_Float16*)(ws + WS_EL);
  float*    x2 = (float*)(ws + WS_X2);
  float*    e2 = (float*)(ws + WS_E2);
  float2*   part = (float2*)(ws + WS_PART);

  float* quant = (float*)d_out;
  float* ind   = (float*)d_out + OFF_IND;
  float* dist  = (float*)d_out + OFF_DIST;

  prep_kernel<<<dim3(NROWS + NCODE), 128, 0, stream>>>(x, embed, xh, xl, eh, el, x2, e2);
  dist_gemm_kernel<<<dim3(NBM * NBN), 512, 0, stream>>>(xh, xl, eh, el, x2, e2, dist, part);
  reduce_gather_kernel<<<dim3(NROWS), 64, 0, stream>>>(part, embed, quant, ind);
}

// Round 3
// 1025.283 us; speedup vs baseline: 1.5389x; 1.0878x over previous
//
#include <hip/hip_runtime.h>
#include <hip/hip_fp16.h>
#include <stdint.h>

typedef _Float16 f16x8 __attribute__((ext_vector_type(8)));
typedef _Float16 f16x4 __attribute__((ext_vector_type(4)));
typedef float    f32x4 __attribute__((ext_vector_type(4)));

static constexpr int NROWS = 32768;   // b*n
static constexpr int NCODE = 8192;
static constexpr int DDIM  = 512;
static constexpr int BM = 256, BN = 256, BK = 64;
static constexpr int NBM = NROWS / BM;    // 128
static constexpr int NBN = NCODE / BN;    // 32
static constexpr int NPART = NBN * 2;     // 64 partials per row

// out layout (floats): quantize [NROWS*DDIM] | embed_ind [NROWS] | dist [NROWS*NCODE]
static constexpr size_t OFF_IND  = (size_t)NROWS * DDIM;
static constexpr size_t OFF_DIST = OFF_IND + NROWS;

// ws layout (bytes)
static constexpr size_t WS_XH   = 0;
static constexpr size_t WS_XL   = WS_XH + (size_t)NROWS * DDIM * 2;
static constexpr size_t WS_EH   = WS_XL + (size_t)NROWS * DDIM * 2;
static constexpr size_t WS_EL   = WS_EH + (size_t)NCODE * DDIM * 2;
static constexpr size_t WS_X2   = WS_EL + (size_t)NCODE * DDIM * 2;
static constexpr size_t WS_E2   = WS_X2 + (size_t)NROWS * 4;
static constexpr size_t WS_PART = WS_E2 + (size_t)NCODE * 4;

__device__ inline void gload_lds16(const void* g, void* l) {
  __builtin_amdgcn_global_load_lds((const __attribute__((address_space(1))) void*)g,
                                   (__attribute__((address_space(3))) void*)l,
                                   16, 0, 0);
}

// ---------- prep: fp32 -> (f16 hi, f16 lo) split + fp64-accumulated norms ----------
__global__ __launch_bounds__(128)
void prep_kernel(const float* __restrict__ x, const float* __restrict__ e,
                 _Float16* __restrict__ xh, _Float16* __restrict__ xl,
                 _Float16* __restrict__ eh, _Float16* __restrict__ el,
                 float* __restrict__ x2, float* __restrict__ e2)
{
  int bid = blockIdx.x;
  const float* src; _Float16 *dh, *dl; float* nrm;
  if (bid < NROWS) {
    src = x + (size_t)bid * DDIM;
    dh = xh + (size_t)bid * DDIM;  dl = xl + (size_t)bid * DDIM;
    nrm = x2 + bid;
  } else {
    int r = bid - NROWS;
    src = e + (size_t)r * DDIM;
    dh = eh + (size_t)r * DDIM;    dl = el + (size_t)r * DDIM;
    nrm = e2 + r;
  }
  int t = threadIdx.x;
  float4 v = reinterpret_cast<const float4*>(src)[t];
  double s = (double)v.x*v.x + (double)v.y*v.y + (double)v.z*v.z + (double)v.w*v.w;
  f16x4 h, l;
  h.x = (_Float16)v.x; l.x = (_Float16)(v.x - (float)h.x);
  h.y = (_Float16)v.y; l.y = (_Float16)(v.y - (float)h.y);
  h.z = (_Float16)v.z; l.z = (_Float16)(v.z - (float)h.z);
  h.w = (_Float16)v.w; l.w = (_Float16)(v.w - (float)h.w);
  reinterpret_cast<f16x4*>(dh)[t] = h;
  reinterpret_cast<f16x4*>(dl)[t] = l;
  #pragma unroll
  for (int m = 1; m < 64; m <<= 1) s += __shfl_xor(s, m);
  __shared__ double sh[2];
  if ((t & 63) == 0) sh[t >> 6] = s;
  __syncthreads();
  if (t == 0) nrm[0] = (float)(sh[0] + sh[1]);
}

// ---------- main: 256x256 half-tile-pipelined split-GEMM + dist epilogue + partial argmin ----------
__global__ __launch_bounds__(512, 1)
void dist_gemm_kernel(const _Float16* __restrict__ xh, const _Float16* __restrict__ xl,
                      const _Float16* __restrict__ eh, const _Float16* __restrict__ el,
                      const float* __restrict__ x2, const float* __restrict__ e2,
                      float* __restrict__ dist, float2* __restrict__ part)
{
  __shared__ _Float16 L[2][2][BM * BK];   // [buf][A=0/B=1][256*64] = 128 KiB

  const int tid  = threadIdx.x;
  const int wid  = tid >> 6;
  const int lane = tid & 63;
  const int qwr  = wid >> 1;      // 0..3 : 32-row band within each 128-row half
  const int qwc  = wid & 1;       // 0..1 : 64-col half within each 128-col half

  // XCD-bijective block swizzle (gridDim.x = 4096, divisible by 8)
  const int flat = blockIdx.x;
  const int swz  = (flat & 7) * (int)(gridDim.x >> 3) + (flat >> 3);
  const int bm = swz >> 5;
  const int bn = swz & 31;
  const int R  = bm * BM;
  const int Cc = bn * BN;

  const int l3 = lane >> 3;
  const int l7 = lane & 7;
  const int srcslot = ((l7 ^ l3) << 4);   // pre-swizzled global 16B-slot (inverse of read swizzle)

  // half: 0=A.h0  1=B.h0  2=A.h1  3=B.h1   (2 gloads per wave each)
  auto STAGE_HALF = [&](int t, int nb, int half) {
    const int ab = half & 1;
    const int hh = half >> 1;
    const _Float16* base;
    size_t rowbase;
    if (ab == 0) { base = (t < 16) ? xh : xl;              rowbase = (size_t)R;  }
    else         { base = (t < 8 || t >= 16) ? eh : el;    rowbase = (size_t)Cc; }
    const int k0b = (t & 7) * (BK * 2);
    #pragma unroll
    for (int i = 0; i < 2; ++i) {
      const int rr = hh * 128 + wid * 16 + i * 8;
      gload_lds16((const char*)base + (rowbase + rr + l3) * (DDIM * 2) + k0b + srcslot,
                  &L[nb][ab][rr * BK]);
    }
  };

  const int l15   = lane & 15;
  const int kslot = (lane >> 4) << 4;     // 0,16,32,48 byte k-slot

  auto LDA = [&](f16x8 (&af)[2][2], int b, int mq) {
    #pragma unroll
    for (int m = 0; m < 2; ++m)
      #pragma unroll
      for (int ks = 0; ks < 2; ++ks) {
        const int row = mq * 128 + qwr * 32 + m * 16 + l15;
        const int kb  = (ks * 64 + kslot) ^ ((row & 7) << 4);
        af[m][ks] = *(const f16x8*)((const char*)&L[b][0][0] + row * 128 + kb);
      }
  };
  auto LDB = [&](f16x8 (&bf)[4][2], int b, int nq) {
    #pragma unroll
    for (int n = 0; n < 4; ++n)
      #pragma unroll
      for (int ks = 0; ks < 2; ++ks) {
        const int row = nq * 128 + qwc * 64 + n * 16 + l15;
        const int kb  = (ks * 64 + kslot) ^ ((row & 7) << 4);
        bf[n][ks] = *(const f16x8*)((const char*)&L[b][1][0] + row * 128 + kb);
      }
  };

  f32x4 acc[2][2][2][4] = {};   // [mq][nq][m][n]

  auto MM = [&](f32x4 (&ac)[2][4], f16x8 (&af)[2][2], f16x8 (&bf)[4][2]) {
    #pragma unroll
    for (int m = 0; m < 2; ++m)
      #pragma unroll
      for (int n = 0; n < 4; ++n)
        #pragma unroll
        for (int ks = 0; ks < 2; ++ks)
          ac[m][n] = __builtin_amdgcn_mfma_f32_16x16x32_f16(af[m][ks], bf[n][ks], ac[m][n], 0, 0, 0);
  };

  // prologue: all 4 halves of tile 0 -> buf 0 (8 loads in flight)
  STAGE_HALF(0, 0, 0);
  STAGE_HALF(0, 0, 1);
  STAGE_HALF(0, 0, 2);
  STAGE_HALF(0, 0, 3);

  for (int t = 0; t < 24; ++t) {
    const int b = t & 1;
    f16x8 af0[2][2], af1[2][2], bf0[4][2], bf1[4][2];

    // ---- p1: quadrant (0,0) — needs A.h0, B.h0 ----
    if (t < 23) { STAGE_HALF(t + 1, b ^ 1, 0);
                  asm volatile("s_waitcnt vmcnt(6)" ::: "memory"); }
    else        { asm volatile("s_waitcnt vmcnt(4)" ::: "memory"); }
    __builtin_amdgcn_s_barrier();
    LDA(af0, b, 0);
    LDB(bf0, b, 0);
    __builtin_amdgcn_s_setprio(1);
    MM(acc[0][0], af0, bf0);
    __builtin_amdgcn_s_setprio(0);
    __builtin_amdgcn_s_barrier();

    // ---- p2: quadrant (1,0) — needs A.h1 (B.h0 in regs) ----
    if (t < 23) { STAGE_HALF(t + 1, b ^ 1, 1);
                  asm volatile("s_waitcnt vmcnt(6)" ::: "memory"); }
    else        { asm volatile("s_waitcnt vmcnt(2)" ::: "memory"); }
    __builtin_amdgcn_s_barrier();
    LDA(af1, b, 1);
    __builtin_amdgcn_s_setprio(1);
    MM(acc[1][0], af1, bf0);
    __builtin_amdgcn_s_setprio(0);
    __builtin_amdgcn_s_barrier();

    // ---- p3: quadrant (1,1) — needs B.h1 (A.h1 in regs) ----
    if (t < 23) { STAGE_HALF(t + 1, b ^ 1, 2);
                  asm volatile("s_waitcnt vmcnt(6)" ::: "memory"); }
    else        { asm volatile("s_waitcnt vmcnt(0)" ::: "memory"); }
    __builtin_amdgcn_s_barrier();
    LDB(bf1, b, 1);
    __builtin_amdgcn_s_setprio(1);
    MM(acc[1][1], af1, bf1);
    __builtin_amdgcn_s_setprio(0);
    __builtin_amdgcn_s_barrier();

    // ---- p4: quadrant (0,1) — all operands already in regs; no wait ----
    if (t < 23) STAGE_HALF(t + 1, b ^ 1, 3);
    __builtin_amdgcn_s_setprio(1);
    MM(acc[0][1], af0, bf1);
    __builtin_amdgcn_s_setprio(0);
    __builtin_amdgcn_s_barrier();
  }

  // ---- epilogue: dist + per-wave per-row argmin ----
  const int q    = lane >> 4;
  const int csub = lane & 15;

  float e2v[2][4];
  #pragma unroll
  for (int nq = 0; nq < 2; ++nq)
    #pragma unroll
    for (int n = 0; n < 4; ++n)
      e2v[nq][n] = e2[Cc + nq * 128 + qwc * 64 + n * 16 + csub];

  float bestv[16], besti[16];
  int rix = 0;
  #pragma unroll
  for (int mq = 0; mq < 2; ++mq)
    #pragma unroll
    for (int m = 0; m < 2; ++m)
      #pragma unroll
      for (int j = 0; j < 4; ++j, ++rix) {
        const int row = R + mq * 128 + qwr * 32 + m * 16 + q * 4 + j;
        const float xv = x2[row];
        float* drow = dist + (size_t)row * NCODE;
        float bv = -3.0e38f, bi = 0.0f;
        #pragma unroll
        for (int nq = 0; nq < 2; ++nq)
          #pragma unroll
          for (int n = 0; n < 4; ++n) {
            const int col = Cc + nq * 128 + qwc * 64 + n * 16 + csub;
            float xe = acc[mq][nq][m][n][j];
            float d2 = fmaxf((xv + e2v[nq][n]) - 2.0f * xe, 0.0f);
            float dv = -sqrtf(d2);
            __builtin_nontemporal_store(dv, &drow[col]);   // keep B panels L3-resident
            if (dv > bv) { bv = dv; bi = (float)col; }     // cols ascending => first-max kept
          }
        bestv[rix] = bv;
        besti[rix] = bi;
      }

  // reduce across the 16 lanes sharing each row
  #pragma unroll
  for (int msk = 1; msk < 16; msk <<= 1) {
    #pragma unroll
    for (int r = 0; r < 16; ++r) {
      float ov = __shfl_xor(bestv[r], msk);
      float oi = __shfl_xor(besti[r], msk);
      if (ov > bestv[r] || (ov == bestv[r] && oi < besti[r])) { bestv[r] = ov; besti[r] = oi; }
    }
  }
  if (csub == 0) {
    int rr = 0;
    #pragma unroll
    for (int mq = 0; mq < 2; ++mq)
      #pragma unroll
      for (int m = 0; m < 2; ++m)
        #pragma unroll
        for (int j = 0; j < 4; ++j, ++rr) {
          const int row = R + mq * 128 + qwr * 32 + m * 16 + q * 4 + j;
          part[(size_t)row * NPART + bn * 2 + qwc] = make_float2(bestv[rr], besti[rr]);
        }
  }
}

// ---------- final: per-row reduce of 64 partials, write index, gather code row ----------
__global__ __launch_bounds__(64)
void reduce_gather_kernel(const float2* __restrict__ part, const float* __restrict__ embed,
                          float* __restrict__ quant, float* __restrict__ ind)
{
  const int row = blockIdx.x;
  const int l = threadIdx.x;
  float2 a = part[(size_t)row * NPART + l];
  float bv = a.x, bi = a.y;
  #pragma unroll
  for (int m = 1; m < 64; m <<= 1) {
    float ov = __shfl_xor(bv, m);
    float oi = __shfl_xor(bi, m);
    if (ov > bv || (ov == bv && oi < bi)) { bv = ov; bi = oi; }
  }
  if (l == 0) ind[row] = bi;
  const int idx = (int)bi;
  const float4* src = reinterpret_cast<const float4*>(embed + (size_t)idx * DDIM);
  float4* dst = reinterpret_cast<float4*>(quant + (size_t)row * DDIM);
  dst[l]      = src[l];
  dst[l + 64] = src[l + 64];
}

extern "C" void kernel_launch(void* const* d_in, const int* in_sizes, int n_in,
                              void* d_out, int out_size, void* d_ws, size_t ws_size,
                              hipStream_t stream) {
  const float* x     = (const float*)d_in[0];
  const float* embed = (const float*)d_in[1];

  char* ws = (char*)d_ws;
  _Float16* xh = (_Float16*)(ws + WS_XH);
  _Float16* xl = (_Float16*)(ws + WS_XL);
  _Float16* eh = (_Float16*)(ws + WS_EH);
  _Float16* el = (_Float16*)(ws + WS_EL);
  float*    x2 = (float*)(ws + WS_X2);
  float*    e2 = (float*)(ws + WS_E2);
  float2*   part = (float2*)(ws + WS_PART);

  float* quant = (float*)d_out;
  float* ind   = (float*)d_out + OFF_IND;
  float* dist  = (float*)d_out + OFF_DIST;

  prep_kernel<<<dim3(NROWS + NCODE), 128, 0, stream>>>(x, embed, xh, xl, eh, el, x2, e2);
  dist_gemm_kernel<<<dim3(NBM * NBN), 512, 0, stream>>>(xh, xl, eh, el, x2, e2, dist, part);
  reduce_gather_kernel<<<dim3(NROWS), 64, 0, stream>>>(part, embed, quant, ind);
}

// Round 4
// 998.849 us; speedup vs baseline: 1.5796x; 1.0265x over previous
//
#include <hip/hip_runtime.h>
#include <hip/hip_fp16.h>
#include <stdint.h>

typedef _Float16 f16x8 __attribute__((ext_vector_type(8)));
typedef _Float16 f16x4 __attribute__((ext_vector_type(4)));
typedef float    f32x4 __attribute__((ext_vector_type(4)));

static constexpr int NROWS = 32768;   // b*n
static constexpr int NCODE = 8192;
static constexpr int DDIM  = 512;
static constexpr int BM = 256, BN = 256, BK = 64;
static constexpr int NBM = NROWS / BM;    // 128
static constexpr int NBN = NCODE / BN;    // 32
static constexpr int NPART = NBN * 2;     // 64 partials per row

// out layout (floats): quantize [NROWS*DDIM] | embed_ind [NROWS] | dist [NROWS*NCODE]
static constexpr size_t OFF_IND  = (size_t)NROWS * DDIM;
static constexpr size_t OFF_DIST = OFF_IND + NROWS;

// ws layout (bytes)
static constexpr size_t WS_XH   = 0;
static constexpr size_t WS_XL   = WS_XH + (size_t)NROWS * DDIM * 2;
static constexpr size_t WS_EH   = WS_XL + (size_t)NROWS * DDIM * 2;
static constexpr size_t WS_EL   = WS_EH + (size_t)NCODE * DDIM * 2;
static constexpr size_t WS_X2   = WS_EL + (size_t)NCODE * DDIM * 2;
static constexpr size_t WS_E2   = WS_X2 + (size_t)NROWS * 4;
static constexpr size_t WS_PART = WS_E2 + (size_t)NCODE * 4;

__device__ inline void gload_lds16(const void* g, void* l) {
  __builtin_amdgcn_global_load_lds((const __attribute__((address_space(1))) void*)g,
                                   (__attribute__((address_space(3))) void*)l,
                                   16, 0, 0);
}

// ---------- prep: fp32 -> (f16 hi, f16 lo) split + fp64-accumulated norms ----------
__global__ __launch_bounds__(128)
void prep_kernel(const float* __restrict__ x, const float* __restrict__ e,
                 _Float16* __restrict__ xh, _Float16* __restrict__ xl,
                 _Float16* __restrict__ eh, _Float16* __restrict__ el,
                 float* __restrict__ x2, float* __restrict__ e2)
{
  int bid = blockIdx.x;
  const float* src; _Float16 *dh, *dl; float* nrm;
  if (bid < NROWS) {
    src = x + (size_t)bid * DDIM;
    dh = xh + (size_t)bid * DDIM;  dl = xl + (size_t)bid * DDIM;
    nrm = x2 + bid;
  } else {
    int r = bid - NROWS;
    src = e + (size_t)r * DDIM;
    dh = eh + (size_t)r * DDIM;    dl = el + (size_t)r * DDIM;
    nrm = e2 + r;
  }
  int t = threadIdx.x;
  float4 v = reinterpret_cast<const float4*>(src)[t];
  double s = (double)v.x*v.x + (double)v.y*v.y + (double)v.z*v.z + (double)v.w*v.w;
  f16x4 h, l;
  h.x = (_Float16)v.x; l.x = (_Float16)(v.x - (float)h.x);
  h.y = (_Float16)v.y; l.y = (_Float16)(v.y - (float)h.y);
  h.z = (_Float16)v.z; l.z = (_Float16)(v.z - (float)h.z);
  h.w = (_Float16)v.w; l.w = (_Float16)(v.w - (float)h.w);
  reinterpret_cast<f16x4*>(dh)[t] = h;
  reinterpret_cast<f16x4*>(dl)[t] = l;
  #pragma unroll
  for (int m = 1; m < 64; m <<= 1) s += __shfl_xor(s, m);
  __shared__ double sh[2];
  if ((t & 63) == 0) sh[t >> 6] = s;
  __syncthreads();
  if (t == 0) nrm[0] = (float)(sh[0] + sh[1]);
}

// ---------- main: 256x256 half-tile-pipelined split-GEMM + dist epilogue + partial argmin ----------
__global__ __launch_bounds__(512, 1)
void dist_gemm_kernel(const _Float16* __restrict__ xh, const _Float16* __restrict__ xl,
                      const _Float16* __restrict__ eh, const _Float16* __restrict__ el,
                      const float* __restrict__ x2, const float* __restrict__ e2,
                      float* __restrict__ dist, float2* __restrict__ part)
{
  __shared__ _Float16 L[2][2][BM * BK];   // [buf][A=0/B=1][256*64] = 128 KiB

  const int tid  = threadIdx.x;
  const int wid  = tid >> 6;
  const int lane = tid & 63;
  const int qwr  = wid >> 1;      // 0..3 : 32-row band within each 128-row half
  const int qwc  = wid & 1;       // 0..1 : 64-col half within each 128-col half

  // Locality swizzle: each XCD owns a fixed 4-wide bn strip (2 MB B panel -> L2-resident);
  // all XCDs sweep bm in the same order so A panels are L3-shared within a short window.
  const int flat = blockIdx.x;
  const int xcd  = flat & 7;
  const int idx  = flat >> 3;          // 0..511
  const int bn   = xcd * 4 + (idx & 3);
  const int bm   = idx >> 2;           // 0..127
  const int R  = bm * BM;
  const int Cc = bn * BN;

  const int l3 = lane >> 3;
  const int l7 = lane & 7;
  const int srcslot = ((l7 ^ l3) << 4);   // pre-swizzled global 16B-slot (inverse of read swizzle)

  // half: 0=A.h0  1=B.h0  2=A.h1  3=B.h1   (2 gloads per wave each)
  auto STAGE_HALF = [&](int t, int nb, int half) {
    const int ab = half & 1;
    const int hh = half >> 1;
    const _Float16* base;
    size_t rowbase;
    if (ab == 0) { base = (t < 16) ? xh : xl;              rowbase = (size_t)R;  }
    else         { base = (t < 8 || t >= 16) ? eh : el;    rowbase = (size_t)Cc; }
    const int k0b = (t & 7) * (BK * 2);
    #pragma unroll
    for (int i = 0; i < 2; ++i) {
      const int rr = hh * 128 + wid * 16 + i * 8;
      gload_lds16((const char*)base + (rowbase + rr + l3) * (DDIM * 2) + k0b + srcslot,
                  &L[nb][ab][rr * BK]);
    }
  };

  const int l15   = lane & 15;
  const int kslot = (lane >> 4) << 4;     // 0,16,32,48 byte k-slot

  auto LDA = [&](f16x8 (&af)[2][2], int b, int mq) {
    #pragma unroll
    for (int m = 0; m < 2; ++m)
      #pragma unroll
      for (int ks = 0; ks < 2; ++ks) {
        const int row = mq * 128 + qwr * 32 + m * 16 + l15;
        const int kb  = (ks * 64 + kslot) ^ ((row & 7) << 4);
        af[m][ks] = *(const f16x8*)((const char*)&L[b][0][0] + row * 128 + kb);
      }
  };
  auto LDB = [&](f16x8 (&bf)[4][2], int b, int nq) {
    #pragma unroll
    for (int n = 0; n < 4; ++n)
      #pragma unroll
      for (int ks = 0; ks < 2; ++ks) {
        const int row = nq * 128 + qwc * 64 + n * 16 + l15;
        const int kb  = (ks * 64 + kslot) ^ ((row & 7) << 4);
        bf[n][ks] = *(const f16x8*)((const char*)&L[b][1][0] + row * 128 + kb);
      }
  };

  f32x4 acc[2][2][2][4] = {};   // [mq][nq][m][n]

  auto MM = [&](f32x4 (&ac)[2][4], f16x8 (&af)[2][2], f16x8 (&bf)[4][2]) {
    #pragma unroll
    for (int m = 0; m < 2; ++m)
      #pragma unroll
      for (int n = 0; n < 4; ++n)
        #pragma unroll
        for (int ks = 0; ks < 2; ++ks)
          ac[m][n] = __builtin_amdgcn_mfma_f32_16x16x32_f16(af[m][ks], bf[n][ks], ac[m][n], 0, 0, 0);
  };

  // prologue: all 4 halves of tile 0 -> buf 0 (8 loads in flight)
  STAGE_HALF(0, 0, 0);
  STAGE_HALF(0, 0, 1);
  STAGE_HALF(0, 0, 2);
  STAGE_HALF(0, 0, 3);

  for (int t = 0; t < 24; ++t) {
    const int b = t & 1;
    f16x8 af0[2][2], af1[2][2], bf0[4][2], bf1[4][2];

    // ---- p1: quadrant (0,0) — needs A.h0, B.h0 ----
    if (t < 23) { STAGE_HALF(t + 1, b ^ 1, 0);
                  asm volatile("s_waitcnt vmcnt(6)" ::: "memory"); }
    else        { asm volatile("s_waitcnt vmcnt(4)" ::: "memory"); }
    __builtin_amdgcn_s_barrier();
    LDA(af0, b, 0);
    LDB(bf0, b, 0);
    __builtin_amdgcn_s_setprio(1);
    MM(acc[0][0], af0, bf0);
    __builtin_amdgcn_s_setprio(0);
    __builtin_amdgcn_s_barrier();

    // ---- p2: quadrant (1,0) — needs A.h1 (B.h0 in regs) ----
    if (t < 23) { STAGE_HALF(t + 1, b ^ 1, 1);
                  asm volatile("s_waitcnt vmcnt(6)" ::: "memory"); }
    else        { asm volatile("s_waitcnt vmcnt(2)" ::: "memory"); }
    __builtin_amdgcn_s_barrier();
    LDA(af1, b, 1);
    __builtin_amdgcn_s_setprio(1);
    MM(acc[1][0], af1, bf0);
    __builtin_amdgcn_s_setprio(0);
    __builtin_amdgcn_s_barrier();

    // ---- p3: quadrant (1,1) — needs B.h1 (A.h1 in regs) ----
    if (t < 23) { STAGE_HALF(t + 1, b ^ 1, 2);
                  asm volatile("s_waitcnt vmcnt(6)" ::: "memory"); }
    else        { asm volatile("s_waitcnt vmcnt(0)" ::: "memory"); }
    __builtin_amdgcn_s_barrier();
    LDB(bf1, b, 1);
    __builtin_amdgcn_s_setprio(1);
    MM(acc[1][1], af1, bf1);
    __builtin_amdgcn_s_setprio(0);
    __builtin_amdgcn_s_barrier();

    // ---- p4: quadrant (0,1) — all operands already in regs; no wait ----
    if (t < 23) STAGE_HALF(t + 1, b ^ 1, 3);
    __builtin_amdgcn_s_setprio(1);
    MM(acc[0][1], af0, bf1);
    __builtin_amdgcn_s_setprio(0);
    __builtin_amdgcn_s_barrier();
  }

  // ---- epilogue: dist + per-wave per-row argmin ----
  const int q    = lane >> 4;
  const int csub = lane & 15;

  float e2v[2][4];
  #pragma unroll
  for (int nq = 0; nq < 2; ++nq)
    #pragma unroll
    for (int n = 0; n < 4; ++n)
      e2v[nq][n] = e2[Cc + nq * 128 + qwc * 64 + n * 16 + csub];

  float bestv[16], besti[16];
  int rix = 0;
  #pragma unroll
  for (int mq = 0; mq < 2; ++mq)
    #pragma unroll
    for (int m = 0; m < 2; ++m)
      #pragma unroll
      for (int j = 0; j < 4; ++j, ++rix) {
        const int row = R + mq * 128 + qwr * 32 + m * 16 + q * 4 + j;
        const float xv = x2[row];
        float* drow = dist + (size_t)row * NCODE;
        float bv = -3.0e38f, bi = 0.0f;
        #pragma unroll
        for (int nq = 0; nq < 2; ++nq)
          #pragma unroll
          for (int n = 0; n < 4; ++n) {
            const int col = Cc + nq * 128 + qwc * 64 + n * 16 + csub;
            float xe = acc[mq][nq][m][n][j];
            float d2 = fmaxf((xv + e2v[nq][n]) - 2.0f * xe, 0.0f);
            float dv = -sqrtf(d2);
            drow[col] = dv;
            if (dv > bv) { bv = dv; bi = (float)col; }     // cols ascending => first-max kept
          }
        bestv[rix] = bv;
        besti[rix] = bi;
      }

  // reduce across the 16 lanes sharing each row
  #pragma unroll
  for (int msk = 1; msk < 16; msk <<= 1) {
    #pragma unroll
    for (int r = 0; r < 16; ++r) {
      float ov = __shfl_xor(bestv[r], msk);
      float oi = __shfl_xor(besti[r], msk);
      if (ov > bestv[r] || (ov == bestv[r] && oi < besti[r])) { bestv[r] = ov; besti[r] = oi; }
    }
  }
  if (csub == 0) {
    int rr = 0;
    #pragma unroll
    for (int mq = 0; mq < 2; ++mq)
      #pragma unroll
      for (int m = 0; m < 2; ++m)
        #pragma unroll
        for (int j = 0; j < 4; ++j, ++rr) {
          const int row = R + mq * 128 + qwr * 32 + m * 16 + q * 4 + j;
          part[(size_t)row * NPART + bn * 2 + qwc] = make_float2(bestv[rr], besti[rr]);
        }
  }
}

// ---------- final: per-row reduce of 64 partials, write index, gather code row ----------
__global__ __launch_bounds__(64)
void reduce_gather_kernel(const float2* __restrict__ part, const float* __restrict__ embed,
                          float* __restrict__ quant, float* __restrict__ ind)
{
  const int row = blockIdx.x;
  const int l = threadIdx.x;
  float2 a = part[(size_t)row * NPART + l];
  float bv = a.x, bi = a.y;
  #pragma unroll
  for (int m = 1; m < 64; m <<= 1) {
    float ov = __shfl_xor(bv, m);
    float oi = __shfl_xor(bi, m);
    if (ov > bv || (ov == bv && oi < bi)) { bv = ov; bi = oi; }
  }
  if (l == 0) ind[row] = bi;
  const int idx = (int)bi;
  const float4* src = reinterpret_cast<const float4*>(embed + (size_t)idx * DDIM);
  float4* dst = reinterpret_cast<float4*>(quant + (size_t)row * DDIM);
  dst[l]      = src[l];
  dst[l + 64] = src[l + 64];
}

extern "C" void kernel_launch(void* const* d_in, const int* in_sizes, int n_in,
                              void* d_out, int out_size, void* d_ws, size_t ws_size,
                              hipStream_t stream) {
  const float* x     = (const float*)d_in[0];
  const float* embed = (const float*)d_in[1];

  char* ws = (char*)d_ws;
  _Float16* xh = (_Float16*)(ws + WS_XH);
  _Float16* xl = (_Float16*)(ws + WS_XL);
  _Float16* eh = (_Float16*)(ws + WS_EH);
  _Float16* el = (_Float16*)(ws + WS_EL);
  float*    x2 = (float*)(ws + WS_X2);
  float*    e2 = (float*)(ws + WS_E2);
  float2*   part = (float2*)(ws + WS_PART);

  float* quant = (float*)d_out;
  float* ind   = (float*)d_out + OFF_IND;
  float* dist  = (float*)d_out + OFF_DIST;

  prep_kernel<<<dim3(NROWS + NCODE), 128, 0, stream>>>(x, embed, xh, xl, eh, el, x2, e2);
  dist_gemm_kernel<<<dim3(NBM * NBN), 512, 0, stream>>>(xh, xl, eh, el, x2, e2, dist, part);
  reduce_gather_kernel<<<dim3(NROWS), 64, 0, stream>>>(part, embed, quant, ind);
}